// Round 12
// baseline (172.265 us; speedup 1.0000x reference)
//
#include <hip/hip_runtime.h>

#define H 256
#define W 256
#define W4 (W / 4)            // 64 float4 per image row
#define OWID 250
#define BAND 10               // output rows per wave; 25*10 = 250
#define NBANDS 25
#define NBLK 6400             // waves / partials
#define RIN 16                // input rows per band
#define WPB 4                 // waves per block
#define NBLOCKS (NBLK / WPB)  // 1600 blocks
#define SLOTF 512             // floats per ring slot (X row 256 + Y row 256)

// Measured landmines (do not regress):
//  - R3/R4: ANY min-waves arg on __launch_bounds__ -> allocator spills. Plain only.
//  - R6: re-rolling the row loop regressed. Keep full static unroll.
//  - R6/R8: L3-resident dispatches run same time as HBM -> latency, not BW.
//  - R7/R11: dual-stream ILP needs >64 VGPR (104-112) -> residency halves. Dead end.
//  - R9 failure causes (all fixed here): per-step lgkmcnt(0) drains; WPB=2
//    (8 waves/CU); VGPR 88. This round: NO lgkmcnt drains, WPB=4 (16 waves/CU
//    at 40KB LDS), minimal VGPR state (moments + transients only).
//  Mechanism under test: global_load_lds stages consume ZERO VGPRs, so the
//  counted vmcnt(6) keeps ~6KB/wave genuinely in flight — breaking the
//  register-slack serialization that pins every VGPR-destination variant
//  at ~500-700cy per load.

__device__ __forceinline__ float4 f4zero() { return make_float4(0.f, 0.f, 0.f, 0.f); }

// SSIM constants with 1/49 (=a) and 49/48 (=covn) folded in.
#define CC1 1e-4f             // (0.01)^2
#define CC2 9e-4f             // (0.03)^2
#define KAA (1.f / 2401.f)    // a^2
#define K2A (2.f / 2401.f)    // 2 a^2
#define KT1 (1.f / 24.f)      // 2 covn a
#define KT2 (-1.f / 1176.f)   // -2 covn a^2
#define KT3 (1.f / 48.f)      // covn a
#define KT4 (-1.f / 2352.f)   // -covn a^2

// Async global->LDS DMA: 16B/lane; LDS dest = wave-uniform base + lane*16;
// global src is per-lane. Counts against vmcnt. (R9-verified correct.)
__device__ __forceinline__ void stage(const float4* g, float* l) {
    __builtin_amdgcn_global_load_lds(
        (const __attribute__((address_space(1))) unsigned int*)g,
        (__attribute__((address_space(3))) unsigned int*)l,
        16, 0, 0);
}

// Counted wait + scheduler fence (rule #18: sched_barrier after asm waitcnt).
template<int N> __device__ __forceinline__ void wait_vm() {
    if constexpr (N >= 6)      asm volatile("s_waitcnt vmcnt(6)" ::: "memory");
    else if constexpr (N == 4) asm volatile("s_waitcnt vmcnt(4)" ::: "memory");
    else if constexpr (N == 2) asm volatile("s_waitcnt vmcnt(2)" ::: "memory");
    else                       asm volatile("s_waitcnt vmcnt(0)" ::: "memory");
    __builtin_amdgcn_sched_barrier(0);
}

// Ledger-derived wait counts (enumerated over all 16 steps; stage order per
// step = leave first, then enter):
//   R<=5: 4   (prologue/enter-only window)
//   6<=R<=13: 6  (steady: 2 steps' stages minus consumed)
//   R=14: 4   R=15: 0 (drain tail)
template<int R> constexpr int nwait() {
    return (R <= 5) ? 4 : (R <= 13) ? 6 : (R == 14) ? 4 : 0;
}

struct M4 { float4 sx, sy, sxy, spp; };

__device__ __forceinline__ void slide(M4& m, const float4 xn, const float4 yn,
                                      const float4 xo, const float4 yo) {
    m.sx.x += xn.x - xo.x; m.sx.y += xn.y - xo.y;
    m.sx.z += xn.z - xo.z; m.sx.w += xn.w - xo.w;
    m.sy.x += yn.x - yo.x; m.sy.y += yn.y - yo.y;
    m.sy.z += yn.z - yo.z; m.sy.w += yn.w - yo.w;
    m.sxy.x = fmaf(xn.x, yn.x, fmaf(-xo.x, yo.x, m.sxy.x));
    m.sxy.y = fmaf(xn.y, yn.y, fmaf(-xo.y, yo.y, m.sxy.y));
    m.sxy.z = fmaf(xn.z, yn.z, fmaf(-xo.z, yo.z, m.sxy.z));
    m.sxy.w = fmaf(xn.w, yn.w, fmaf(-xo.w, yo.w, m.sxy.w));
    m.spp.x = fmaf(xn.x, xn.x, fmaf(yn.x, yn.x, fmaf(-xo.x, xo.x, fmaf(-yo.x, yo.x, m.spp.x))));
    m.spp.y = fmaf(xn.y, xn.y, fmaf(yn.y, yn.y, fmaf(-xo.y, xo.y, fmaf(-yo.y, yo.y, m.spp.y))));
    m.spp.z = fmaf(xn.z, xn.z, fmaf(yn.z, yn.z, fmaf(-xo.z, xo.z, fmaf(-yo.z, yo.z, m.spp.z))));
    m.spp.w = fmaf(xn.w, xn.w, fmaf(yn.w, yn.w, fmaf(-xo.w, xo.w, fmaf(-yo.w, yo.w, m.spp.w))));
}

// Horizontal 7-tap via prefix decomposition (R8-verified): 4 shuffles/moment.
__device__ __forceinline__ void hwin4(const float4 S, float w[4]) {
    const float p1 = S.x;
    const float p2 = p1 + S.y;
    const float p3 = p2 + S.z;
    const float E  = p3 + S.w;
    const float n3 = __shfl_down(p3, 1);
    const float nE = __shfl_down(E, 1);
    const float f1 = __shfl_down(p1, 2);
    const float f2 = __shfl_down(p2, 2);
    w[0] = E + n3;
    w[1] = (E - p1) + nE;
    w[2] = (E - p2) + nE + f1;
    w[3] = (E - p3) + nE + f2;
}

// One output row's windows + SSIM + masked accumulate (R8-verified).
__device__ __forceinline__ void outrow(const M4& m, const float m01,
                                       const float m23, float& lsum) {
    float wx[4], wy[4], wpp[4], wxy[4];
    hwin4(m.sx,  wx);
    hwin4(m.sy,  wy);
    hwin4(m.spp, wpp);
    hwin4(m.sxy, wxy);
    #pragma unroll
    for (int s = 0; s < 4; ++s) {
        const float P  = wx[s] * wy[s];
        const float Qs = fmaf(wy[s], wy[s], wx[s] * wx[s]);
        const float A1 = fmaf(K2A, P, CC1);
        const float B1 = fmaf(KAA, Qs, CC1);
        const float A2 = fmaf(KT1, wxy[s], fmaf(KT2, P, CC2));
        const float B2 = fmaf(KT3, wpp[s], fmaf(KT4, Qs, CC2));
        const float S  = (A1 * A2) * __builtin_amdgcn_rcpf(B1 * B2);
        lsum = fmaf(S, (s < 2) ? m01 : m23, lsum);  // branchless col mask
    }
}

template<int R>
__device__ __forceinline__ void step(const float4* Xp, const float4* Yp,
                                     float* exl, float* lvl, const int lo4,
                                     M4& m, const float m01, const float m23,
                                     float& lsum)
{
    // (1) stage leave row R-6 -> slot (R-6)%2 (consumed next step as row R-6).
    if constexpr (R >= 6 && R <= 14) {
        stage(Xp + (R - 6) * W4, lvl + ((R - 6) % 2) * SLOTF);
        stage(Yp + (R - 6) * W4, lvl + ((R - 6) % 2) * SLOTF + 256);
    }
    // (2) stage enter row R+2 -> slot (R+2)%3.
    if constexpr (R + 2 < RIN) {
        stage(Xp + (R + 2) * W4, exl + ((R + 2) % 3) * SLOTF);
        stage(Yp + (R + 2) * W4, exl + ((R + 2) % 3) * SLOTF + 256);
    }
    // (3) one counted wait: row R's and leave (R-7)'s stages have landed;
    //     up to 6 newer stages stay in flight across steps.
    wait_vm<nwait<R>()>();

    // (4) ds_read this step's rows from the rings.
    const float4 xn = *(const float4*)(exl + (R % 3) * SLOTF + lo4);
    const float4 yn = *(const float4*)(exl + (R % 3) * SLOTF + 256 + lo4);
    float4 xo = f4zero(), yo = f4zero();
    if constexpr (R >= 7) {
        xo = *(const float4*)(lvl + ((R - 7) % 2) * SLOTF + lo4);
        yo = *(const float4*)(lvl + ((R - 7) % 2) * SLOTF + 256 + lo4);
    }

    // (5) compute.
    slide(m, xn, yn, xo, yo);
    if constexpr (R >= 6) outrow(m, m01, m23, lsum);

    if constexpr (R + 1 < RIN)
        step<R + 1>(Xp, Yp, exl, lvl, lo4, m, m01, m23, lsum);
}

__global__ __launch_bounds__(256) void ssim_band_kernel(
    const float* __restrict__ X, const float* __restrict__ Y,
    float* __restrict__ partial)
{
    // Per-wave private rings: 3 enter slots + 2 leave slots, 2KB each
    // (X row + Y row) = 10KB/wave, 40KB/block -> 4 blocks/CU (16 waves/CU).
    __shared__ float lds[WPB][5 * SLOTF];

    const int lane  = threadIdx.x & 63;         // owns cols 4*lane..4*lane+3
    const int wslot = threadIdx.x >> 6;         // 0..3
    const int wid   = blockIdx.x * WPB + wslot; // 0..6399
    const int img   = wid / NBANDS;             // 0..255
    const int band  = wid % NBANDS;             // 0..24
    const int r0 = band * BAND;

    const float4* Xp = (const float4*)X + ((size_t)img * H + r0) * W4 + lane;
    const float4* Yp = (const float4*)Y + ((size_t)img * H + r0) * W4 + lane;
    float* exl = &lds[wslot][0];                // enter ring (slots 0..2)
    float* lvl = &lds[wslot][3 * SLOTF];        // leave ring (slots 0..1)
    const int lo4 = lane * 4;                   // float offset of this lane's 16B

    M4 m;
    m.sx = f4zero(); m.sy = f4zero(); m.sxy = f4zero(); m.spp = f4zero();

    // Column-validity masks (output cols 0..249).
    const float m01 = (lane <= 62) ? 1.0f : 0.0f;
    const float m23 = (lane <= 61) ? 1.0f : 0.0f;

    // Prologue: stage enter rows 0 and 1.
    stage(Xp,      exl);
    stage(Yp,      exl + 256);
    stage(Xp + W4, exl + SLOTF);
    stage(Yp + W4, exl + SLOTF + 256);

    float lsum = 0.0f;
    step<0>(Xp, Yp, exl, lvl, lo4, m, m01, m23, lsum);

    // Wave reduction -> one partial per wave.
    #pragma unroll
    for (int off = 32; off > 0; off >>= 1)
        lsum += __shfl_down(lsum, off, 64);
    if (lane == 0) partial[wid] = lsum;
}

__global__ __launch_bounds__(256) void ssim_reduce_kernel(
    const float* __restrict__ partial, float* __restrict__ out)
{
    const int tid = threadIdx.x;
    double acc = 0.0;
    for (int i = tid; i < NBLK; i += 256)
        acc += (double)partial[i];
    #pragma unroll
    for (int off = 32; off > 0; off >>= 1)
        acc += __shfl_down(acc, off, 64);
    __shared__ double wsumd[4];
    if ((tid & 63) == 0) wsumd[tid >> 6] = acc;
    __syncthreads();
    if (tid == 0) {
        double total = wsumd[0] + wsumd[1] + wsumd[2] + wsumd[3];
        float loss = (float)(1.0 - total / 16000000.0);
        out[0] = loss; out[1] = loss; out[2] = loss; out[3] = loss;
    }
}

extern "C" void kernel_launch(void* const* d_in, const int* in_sizes, int n_in,
                              void* d_out, int out_size, void* d_ws, size_t ws_size,
                              hipStream_t stream) {
    const float* X = (const float*)d_in[0];
    const float* Y = (const float*)d_in[1];
    // d_in[2] is the uniform 7x7 filter (1/49 everywhere) — constant-folded.
    float* out = (float*)d_out;
    float* partial = (float*)d_ws;   // 6400 floats = 25.6 KB

    hipLaunchKernelGGL(ssim_band_kernel, dim3(NBLOCKS), dim3(256), 0, stream,
                       X, Y, partial);
    hipLaunchKernelGGL(ssim_reduce_kernel, dim3(1), dim3(256), 0, stream,
                       partial, out);
}